// Round 1
// baseline (1259.721 us; speedup 1.0000x reference)
//
#include <hip/hip_runtime.h>

#define B_ 16
#define N_ 4096
#define R_ 256

// V[b,n,i] = (n==i) ? 1 : (n>i ? param[b,n,i] : 0)

// ---------------------------------------------------------------------------
// K1: S[b] = V[b]^T V[b]   (full 256x256 per batch; only upper+diag consumed)
// grid (4,4,16): k0 = x*64, j0 = y*64, b = z.  block 256.
// ---------------------------------------------------------------------------
__global__ __launch_bounds__(256) void gram_kernel(const float* __restrict__ param,
                                                   float* __restrict__ S) {
  const int b  = blockIdx.z;
  const int k0 = blockIdx.x * 64;
  const int j0 = blockIdx.y * 64;
  const float* __restrict__ P = param + (size_t)b * N_ * R_;

  __shared__ float As[32][64];  // [n_sub][j_sub]
  __shared__ float Bs[32][64];  // [n_sub][k_sub]

  const int t  = threadIdx.x;
  const int tx = t & 15;   // k direction (fast -> coalesced stores)
  const int ty = t >> 4;   // j direction

  float acc[4][4];
#pragma unroll
  for (int i = 0; i < 4; ++i)
#pragma unroll
    for (int j = 0; j < 4; ++j) acc[i][j] = 0.f;

  for (int n0 = 0; n0 < N_; n0 += 32) {
#pragma unroll
    for (int m = 0; m < 8; ++m) {
      int idx = t + m * 256;          // 0..2047
      int r = idx >> 6;               // 0..31
      int c = idx & 63;               // 0..63
      int n = n0 + r;
      int j = j0 + c;
      int k = k0 + c;
      float pj = P[(size_t)n * R_ + j];
      float pk = P[(size_t)n * R_ + k];
      As[r][c] = (n == j) ? 1.f : ((n > j) ? pj : 0.f);
      Bs[r][c] = (n == k) ? 1.f : ((n > k) ? pk : 0.f);
    }
    __syncthreads();
#pragma unroll
    for (int kk = 0; kk < 32; ++kk) {
      float a[4], bb[4];
#pragma unroll
      for (int i = 0; i < 4; ++i) a[i]  = As[kk][ty * 4 + i];
#pragma unroll
      for (int i = 0; i < 4; ++i) bb[i] = Bs[kk][tx * 4 + i];
#pragma unroll
      for (int i = 0; i < 4; ++i)
#pragma unroll
        for (int j = 0; j < 4; ++j) acc[i][j] = fmaf(a[i], bb[j], acc[i][j]);
    }
    __syncthreads();
  }

  float* Sb = S + (size_t)b * R_ * R_;
#pragma unroll
  for (int i = 0; i < 4; ++i) {
    int j = j0 + ty * 4 + i;
    int k = k0 + tx * 4;
    float4 v4 = make_float4(acc[i][0], acc[i][1], acc[i][2], acc[i][3]);
    *(float4*)&Sb[(size_t)j * R_ + k] = v4;
  }
}

// ---------------------------------------------------------------------------
// K2: solve (diag(1/tau) + strictU(S)) W = Vtop^T  per batch, backward subst.
// Column k independent: thread-per-column. 32-row left-looking blocking.
// grid (4,16): k = x*64 + tid, b = y.  block 64 (1 wave).  LDS 64 KB.
// Writes zeros for r>k so K3 needs no triangular masking.
// ---------------------------------------------------------------------------
__global__ __launch_bounds__(64) void solve_kernel(const float* __restrict__ param,
                                                   const float* __restrict__ S,
                                                   float* __restrict__ W) {
  const int b   = blockIdx.y;
  const int tid = threadIdx.x;
  const int k   = blockIdx.x * 64 + tid;
  const float* __restrict__ Sb = S + (size_t)b * R_ * R_;
  const float* __restrict__ Pb = param + (size_t)b * N_ * R_;
  float* __restrict__ Wb = W + (size_t)b * R_ * R_;

  __shared__ float wcol[R_ * 64];   // [r][tid], 64 KB — each thread touches only its own column

  for (int rb = R_ - 32; rb >= 0; rb -= 32) {
    // ---- GEMM part: contributions from rows already solved (c >= rb+32) ----
    float accr[32];
#pragma unroll
    for (int i = 0; i < 32; ++i) accr[i] = 0.f;
    for (int c = rb + 32; c <= k; ++c) {       // per-lane trip count; c uniform among actives
      float wc = wcol[c * 64 + tid];
#pragma unroll
      for (int i = 0; i < 32; ++i)
        accr[i] = fmaf(Sb[(size_t)(rb + i) * R_ + c], wc, accr[i]);
    }
    // ---- deposit partial rhs (static accr indexing; rule #20) ----
#pragma unroll
    for (int i = 0; i < 32; ++i) {
      int r = rb + i;
      if (k >= r) {
        float rhs = (k == r) ? 1.f : Pb[(size_t)k * R_ + r];  // Vtop^T[r,k] = V[k,r]
        wcol[r * 64 + tid] = rhs - accr[i];
      }
    }
    // ---- triangular finish within the 32-row block (descending) ----
    for (int i = 31; i >= 0; --i) {
      int r = rb + i;
      if (k >= r) {
        float w = wcol[r * 64 + tid];
        int cend = min(rb + 32, k + 1);
        for (int c = r + 1; c < cend; ++c)
          w = fmaf(-Sb[(size_t)r * R_ + c], wcol[c * 64 + tid], w);
        float taur = 2.f / Sb[(size_t)r * R_ + r];
        wcol[r * 64 + tid] = taur * w;
      }
    }
  }
  // ---- write out full column incl. zeros below diagonal ----
  for (int r = 0; r < R_; ++r)
    Wb[(size_t)r * R_ + k] = (r <= k) ? wcol[r * 64 + tid] : 0.f;
}

// ---------------------------------------------------------------------------
// K3: Q[b] = E - V[b] @ W[b]
// grid (64,4,16): n0 = x*64, k0 = y*64, b = z.  block 256.
// j-loop capped at k0+64 (W upper triangular; zeros elsewhere anyway).
// ---------------------------------------------------------------------------
__global__ __launch_bounds__(256) void final_kernel(const float* __restrict__ param,
                                                    const float* __restrict__ W,
                                                    float* __restrict__ Q) {
  const int b  = blockIdx.z;
  const int n0 = blockIdx.x * 64;
  const int k0 = blockIdx.y * 64;
  const float* __restrict__ Pb = param + (size_t)b * N_ * R_;
  const float* __restrict__ Wb = W + (size_t)b * R_ * R_;
  float* __restrict__ Qb = Q + (size_t)b * N_ * R_;

  __shared__ float Vs[64][33];   // [n_sub][j_sub], +1 pad: conflict-free rows
  __shared__ float Ws[32][64];   // [j_sub][k_sub]

  const int t  = threadIdx.x;
  const int tx = t & 15;   // k direction (fast -> coalesced stores)
  const int ty = t >> 4;   // n direction

  float acc[4][4];
#pragma unroll
  for (int i = 0; i < 4; ++i)
#pragma unroll
    for (int j = 0; j < 4; ++j) acc[i][j] = 0.f;

  const int jend = k0 + 64;
  for (int jb = 0; jb < jend; jb += 32) {
#pragma unroll
    for (int m = 0; m < 8; ++m) {            // Vs: 64 x 32
      int idx = t + m * 256;
      int r = idx >> 5;                       // 0..63 (n_sub)
      int c = idx & 31;                       // 0..31 (j_sub)
      int n = n0 + r, j = jb + c;
      float pv = Pb[(size_t)n * R_ + j];
      Vs[r][c] = (n == j) ? 1.f : ((n > j) ? pv : 0.f);
    }
#pragma unroll
    for (int m = 0; m < 8; ++m) {            // Ws: 32 x 64
      int idx = t + m * 256;
      int r = idx >> 6;                       // 0..31 (j_sub)
      int c = idx & 63;                       // 0..63 (k_sub)
      Ws[r][c] = Wb[(size_t)(jb + r) * R_ + (k0 + c)];
    }
    __syncthreads();
#pragma unroll
    for (int kk = 0; kk < 32; ++kk) {
      float a[4], w4[4];
#pragma unroll
      for (int i = 0; i < 4; ++i) a[i]  = Vs[ty * 4 + i][kk];
#pragma unroll
      for (int i = 0; i < 4; ++i) w4[i] = Ws[kk][tx * 4 + i];
#pragma unroll
      for (int i = 0; i < 4; ++i)
#pragma unroll
        for (int j = 0; j < 4; ++j) acc[i][j] = fmaf(a[i], w4[j], acc[i][j]);
    }
    __syncthreads();
  }

#pragma unroll
  for (int i = 0; i < 4; ++i) {
    int n = n0 + ty * 4 + i;
    int kbase = k0 + tx * 4;
    float o[4];
#pragma unroll
    for (int j = 0; j < 4; ++j)
      o[j] = ((n == kbase + j) ? 1.f : 0.f) - acc[i][j];
    *(float4*)&Qb[(size_t)n * R_ + kbase] = make_float4(o[0], o[1], o[2], o[3]);
  }
}

extern "C" void kernel_launch(void* const* d_in, const int* in_sizes, int n_in,
                              void* d_out, int out_size, void* d_ws, size_t ws_size,
                              hipStream_t stream) {
  const float* param = (const float*)d_in[0];
  float* Q = (float*)d_out;
  // S (B*R*R = 4 MB) lives in the first 1M floats of d_out (== Q[b=0]);
  // it is consumed by K2 before K3 overwrites the region with Q. Stream-ordered.
  float* S = Q;
  float* W = (float*)d_ws;   // needs 4 MB of scratch

  dim3 g1(4, 4, B_);
  gram_kernel<<<g1, 256, 0, stream>>>(param, S);

  dim3 g2(4, B_, 1);
  solve_kernel<<<g2, 64, 0, stream>>>(param, S, W);

  dim3 g3(64, 4, B_);
  final_kernel<<<g3, 256, 0, stream>>>(param, W, Q);
}

// Round 2
// 524.922 us; speedup vs baseline: 2.3998x; 2.3998x over previous
//
#include <hip/hip_runtime.h>

#define B_ 16
#define N_ 4096
#define R_ 256

// V[b,n,i] = (n==i) ? 1 : (n>i ? param[b,n,i] : 0)
// Pipeline: S = V^T V (upper tiles, split-K partials) -> reduce -> solve
// (diag(1/tau)+strictU(S)) W = Vtop^T  (wave-per-column) -> Q = E - V W.

// ---------------------------------------------------------------------------
// K1: partial Gram. grid (10 pairs, 8 K-chunks, 16 b), block 256, 4x4/thread.
// Writes SP[chunk][b][256][256] (only upper 64x64 tiles written).
// ---------------------------------------------------------------------------
__global__ __launch_bounds__(256) void gram_kernel(const float* __restrict__ param,
                                                   float* __restrict__ SP) {
  const int pair  = blockIdx.x;
  const int chunk = blockIdx.y;
  const int b     = blockIdx.z;
  // pair -> (jt,kt), jt<=kt, packed 2 bits each
  const int j0 = (int)((0xE9500u >> (2 * pair)) & 3u) * 64;
  const int k0 = (int)((0xFB9E4u >> (2 * pair)) & 3u) * 64;
  const float* __restrict__ P = param + (size_t)b * N_ * R_;

  __shared__ float As[32][64];
  __shared__ float Bs[32][64];

  const int t  = threadIdx.x;
  const int tx = t & 15;   // k dir
  const int ty = t >> 4;   // j dir

  float acc[4][4];
#pragma unroll
  for (int i = 0; i < 4; ++i)
#pragma unroll
    for (int j = 0; j < 4; ++j) acc[i][j] = 0.f;

  const int nb = chunk * 512;
  const int ne = nb + 512;
  int ns = (nb > k0) ? nb : k0;   // rows n < k0 have B==0 -> zero contribution

  for (int n0 = ns; n0 < ne; n0 += 32) {
#pragma unroll
    for (int m = 0; m < 8; ++m) {
      int idx = t + m * 256;
      int r = idx >> 6;
      int c = idx & 63;
      int n = n0 + r;
      float pj = P[(size_t)n * R_ + (j0 + c)];
      float pk = P[(size_t)n * R_ + (k0 + c)];
      As[r][c] = (n == j0 + c) ? 1.f : ((n > j0 + c) ? pj : 0.f);
      Bs[r][c] = (n == k0 + c) ? 1.f : ((n > k0 + c) ? pk : 0.f);
    }
    __syncthreads();
#pragma unroll
    for (int kk = 0; kk < 32; ++kk) {
      float a[4], bb[4];
      *(float4*)a  = *(const float4*)&As[kk][4 * ty];
      *(float4*)bb = *(const float4*)&Bs[kk][4 * tx];
#pragma unroll
      for (int i = 0; i < 4; ++i)
#pragma unroll
        for (int j = 0; j < 4; ++j) acc[i][j] = fmaf(a[i], bb[j], acc[i][j]);
    }
    __syncthreads();
  }

  float* Sp = SP + (size_t)(chunk * 16 + b) * (R_ * R_);
#pragma unroll
  for (int i = 0; i < 4; ++i) {
    int j = j0 + ty * 4 + i;
    *(float4*)&Sp[(size_t)j * R_ + k0 + 4 * tx] =
        make_float4(acc[i][0], acc[i][1], acc[i][2], acc[i][3]);
  }
}

// ---------------------------------------------------------------------------
// reduce: S = sum over 8 chunks of SP. grid 1024, block 256 (float4 each).
// ---------------------------------------------------------------------------
__global__ __launch_bounds__(256) void reduce_kernel(const float* __restrict__ SP,
                                                     float* __restrict__ S) {
  size_t idx = (size_t)blockIdx.x * 256 + threadIdx.x;  // float4 index
  const float4* sp = (const float4*)SP;
  float4 a = sp[idx];
#pragma unroll
  for (int c = 1; c < 8; ++c) {
    float4 v = sp[idx + (size_t)c * 262144];
    a.x += v.x; a.y += v.y; a.z += v.z; a.w += v.w;
  }
  ((float4*)S)[idx] = a;
}

// ---------------------------------------------------------------------------
// K2: wave-per-column backward substitution.
// wv = blockIdx.x*4 + wave; b = wv>>8; k = wv&255. Lane L owns w[4L..4L+3].
// Per 4-row group: coalesced float4 S-row loads, 4 independent butterfly
// reduces (stale w), then owner-lane correction chain. Writes Wt[b][k][r]
// (transposed W) as one coalesced float4 store per lane.
// ---------------------------------------------------------------------------
__global__ __launch_bounds__(256) void solve_kernel(const float* __restrict__ param,
                                                    const float* __restrict__ S,
                                                    float* __restrict__ Wt) {
  const int lane = threadIdx.x & 63;
  const int wv   = blockIdx.x * 4 + (threadIdx.x >> 6);
  const int b    = wv >> 8;
  const int k    = wv & 255;
  const float* __restrict__ Sb = S + (size_t)b * R_ * R_;
  const float* __restrict__ Pb = param + (size_t)b * N_ * R_;

  // rhs column: x[c] = X[c,k] = (c==k)?1:(c<k ? param[b,k,c] : 0)
  float4 x = *(const float4*)(Pb + (size_t)k * R_ + 4 * lane);
  {
    int c0 = 4 * lane;
    x.x = (c0     == k) ? 1.f : ((c0     < k) ? x.x : 0.f);
    x.y = (c0 + 1 == k) ? 1.f : ((c0 + 1 < k) ? x.y : 0.f);
    x.z = (c0 + 2 == k) ? 1.f : ((c0 + 2 < k) ? x.z : 0.f);
    x.w = (c0 + 3 == k) ? 1.f : ((c0 + 3 < k) ? x.w : 0.f);
  }
  float4 w = make_float4(0.f, 0.f, 0.f, 0.f);

  const int k4 = k >> 2;
  const float4* Srow = (const float4*)Sb;  // row r chunk: Srow[r*64 + lane]

  float4 rA0 = Srow[(size_t)(4 * k4 + 0) * 64 + lane];
  float4 rA1 = Srow[(size_t)(4 * k4 + 1) * 64 + lane];
  float4 rA2 = Srow[(size_t)(4 * k4 + 2) * 64 + lane];
  float4 rA3 = Srow[(size_t)(4 * k4 + 3) * 64 + lane];

  for (int r4 = k4;; --r4) {
    const bool more = (r4 > 0);
    float4 rB0, rB1, rB2, rB3;
    if (more) {  // prefetch next group's rows
      rB0 = Srow[(size_t)(4 * r4 - 4) * 64 + lane];
      rB1 = Srow[(size_t)(4 * r4 - 3) * 64 + lane];
      rB2 = Srow[(size_t)(4 * r4 - 2) * 64 + lane];
      rB3 = Srow[(size_t)(4 * r4 - 1) * 64 + lane];
    }
    // per-lane partial dots with current (stale-for-this-group) w
    float s0 = fmaf(rA0.x, w.x, fmaf(rA0.y, w.y, fmaf(rA0.z, w.z, rA0.w * w.w)));
    float s1 = fmaf(rA1.x, w.x, fmaf(rA1.y, w.y, fmaf(rA1.z, w.z, rA1.w * w.w)));
    float s2 = fmaf(rA2.x, w.x, fmaf(rA2.y, w.y, fmaf(rA2.z, w.z, rA2.w * w.w)));
    float s3 = fmaf(rA3.x, w.x, fmaf(rA3.y, w.y, fmaf(rA3.z, w.z, rA3.w * w.w)));
    // 4 independent butterfly all-reduces (pipelined)
#pragma unroll
    for (int m = 1; m < 64; m <<= 1) {
      s0 += __shfl_xor(s0, m);
      s1 += __shfl_xor(s1, m);
      s2 += __shfl_xor(s2, m);
      s3 += __shfl_xor(s3, m);
    }
    // owner-lane correction chain (rows r = 4*r4+3 .. 4*r4)
    // On lane r4: rAj holds S[rj, 4*r4 .. 4*r4+3]; diag S[rj,rj] = slot j.
    float w3 = 2.f * __builtin_amdgcn_rcpf(rA3.w) * (x.w - s3);
    float s2c = fmaf(rA2.w, w3, s2);
    float w2 = 2.f * __builtin_amdgcn_rcpf(rA2.z) * (x.z - s2c);
    float s1c = fmaf(rA1.z, w2, fmaf(rA1.w, w3, s1));
    float w1 = 2.f * __builtin_amdgcn_rcpf(rA1.y) * (x.y - s1c);
    float s0c = fmaf(rA0.y, w1, fmaf(rA0.z, w2, fmaf(rA0.w, w3, s0)));
    float w0 = 2.f * __builtin_amdgcn_rcpf(rA0.x) * (x.x - s0c);
    if (lane == r4) { w.w = w3; w.z = w2; w.y = w1; w.x = w0; }

    if (!more) break;
    rA0 = rB0; rA1 = rB1; rA2 = rB2; rA3 = rB3;
  }

  // Wt[b][k][4*lane .. 4*lane+3] = w  (rows > k stayed 0)
  *(float4*)(Wt + ((size_t)b * R_ + k) * R_ + 4 * lane) = w;
}

// ---------------------------------------------------------------------------
// K3: Q = E - V @ W. grid (32, 2, 16), block 256, 128x128 tile, 8x8/thread
// (4+4 interleave: thread covers cols {4tx..+3} u {64+4tx..+3}, same for rows).
// Reads transposed Wt. j-loop capped at k0+128 (W upper-triangular).
// ---------------------------------------------------------------------------
__global__ __launch_bounds__(256, 4) void final_kernel(const float* __restrict__ param,
                                                       const float* __restrict__ Wt,
                                                       float* __restrict__ Q) {
  const int b  = blockIdx.z;
  const int n0 = blockIdx.x * 128;
  const int k0 = blockIdx.y * 128;
  const float* __restrict__ Pb = param + (size_t)b * N_ * R_;
  const float* __restrict__ Wb = Wt + (size_t)b * R_ * R_;  // Wb[k*256+j] = W[j][k]
  float* __restrict__ Qb = Q + (size_t)b * N_ * R_;

  __shared__ float Vs[32][132];  // [j_sub][n_sub], pad->2-way-free b128 reads
  __shared__ float Ws[32][132];  // [j_sub][k_sub]

  const int t  = threadIdx.x;
  const int tx = t & 15;   // k dir
  const int ty = t >> 4;   // n dir

  float acc[8][8];
#pragma unroll
  for (int i = 0; i < 8; ++i)
#pragma unroll
    for (int j = 0; j < 8; ++j) acc[i][j] = 0.f;

  const int jend = k0 + 128;
  for (int jb = 0; jb < jend; jb += 32) {
#pragma unroll
    for (int m = 0; m < 16; ++m) {
      int idx = t + m * 256;
      int j = idx & 31;
      int n = idx >> 5;
      int gn = n0 + n, gj = jb + j;
      float pv = Pb[(size_t)gn * R_ + gj];
      Vs[j][n] = (gn == gj) ? 1.f : ((gn > gj) ? pv : 0.f);
    }
#pragma unroll
    for (int m = 0; m < 16; ++m) {
      int idx = t + m * 256;
      int j = idx & 31;
      int kc = idx >> 5;
      Ws[j][kc] = Wb[(size_t)(k0 + kc) * R_ + (jb + j)];
    }
    __syncthreads();
#pragma unroll
    for (int kk = 0; kk < 32; ++kk) {
      float a0[4], a1[4], w0[4], w1[4];
      *(float4*)a0 = *(const float4*)&Vs[kk][4 * ty];
      *(float4*)a1 = *(const float4*)&Vs[kk][64 + 4 * ty];
      *(float4*)w0 = *(const float4*)&Ws[kk][4 * tx];
      *(float4*)w1 = *(const float4*)&Ws[kk][64 + 4 * tx];
#pragma unroll
      for (int i = 0; i < 4; ++i)
#pragma unroll
        for (int j = 0; j < 4; ++j) {
          acc[i][j]         = fmaf(a0[i], w0[j], acc[i][j]);
          acc[i][j + 4]     = fmaf(a0[i], w1[j], acc[i][j + 4]);
          acc[i + 4][j]     = fmaf(a1[i], w0[j], acc[i + 4][j]);
          acc[i + 4][j + 4] = fmaf(a1[i], w1[j], acc[i + 4][j + 4]);
        }
    }
    __syncthreads();
  }

#pragma unroll
  for (int i = 0; i < 8; ++i) {
    int n = n0 + ((i < 4) ? (4 * ty + i) : (60 + 4 * ty + i));
    float o0[4], o1[4];
#pragma unroll
    for (int j = 0; j < 4; ++j) {
      int kc0 = k0 + 4 * tx + j;
      int kc1 = k0 + 64 + 4 * tx + j;
      o0[j] = ((n == kc0) ? 1.f : 0.f) - acc[i][j];
      o1[j] = ((n == kc1) ? 1.f : 0.f) - acc[i][j + 4];
    }
    *(float4*)&Qb[(size_t)n * R_ + k0 + 4 * tx]      = *(float4*)o0;
    *(float4*)&Qb[(size_t)n * R_ + k0 + 64 + 4 * tx] = *(float4*)o1;
  }
}

extern "C" void kernel_launch(void* const* d_in, const int* in_sizes, int n_in,
                              void* d_out, int out_size, void* d_ws, size_t ws_size,
                              hipStream_t stream) {
  const float* param = (const float*)d_in[0];
  float* Q  = (float*)d_out;
  // d_out layout during pipeline (all overwritten by K3 at the end):
  //   [0 .. 1M floats)  : S (4 MB)
  //   [8M .. 16M floats): SP partials, 8 chunks x 16 b x 256 x 256 (32 MB)
  float* S  = Q;
  float* SP = Q + (size_t)8 * 1024 * 1024;
  float* Wt = (float*)d_ws;  // 4 MB transposed W

  gram_kernel<<<dim3(10, 8, B_), 256, 0, stream>>>(param, SP);
  reduce_kernel<<<dim3(1024), 256, 0, stream>>>(SP, S);
  solve_kernel<<<dim3(1024), 256, 0, stream>>>(param, S, Wt);
  final_kernel<<<dim3(32, 2, B_), 256, 0, stream>>>(param, Wt, Q);
}

// Round 3
// 484.221 us; speedup vs baseline: 2.6015x; 1.0841x over previous
//
#include <hip/hip_runtime.h>

#define B_ 16
#define N_ 4096
#define R_ 256

// V[b,n,i] = (n==i) ? 1 : (n>i ? param[b,n,i] : 0)
// Pipeline: S = V^T V (3 upper 128x128 tiles, split-K partials) -> reduce ->
// solve (diag(1/tau)+strictU(S)) W = Vtop^T (wave-per-column) -> Q = E - V W.

// ---------------------------------------------------------------------------
// K1: partial Gram, 128x128 tile, 8x8/thread.
// grid (3 tiles, 8 K-chunks of 512 rows, 16 b), block 256.
// tile0=(0,0) tile1=(0,128) tile2=(128,128); diag tiles alias Bs=As.
// Writes SP[chunk][b][256][256] (only the 3 tiles; rest stays garbage*0).
// ---------------------------------------------------------------------------
__global__ __launch_bounds__(256) void gram_kernel(const float* __restrict__ param,
                                                   float* __restrict__ SP) {
  const int tile  = blockIdx.x;
  const int chunk = blockIdx.y;
  const int b     = blockIdx.z;
  const int j0 = (tile == 2) ? 128 : 0;
  const int k0 = (tile == 0) ? 0 : 128;
  const float* __restrict__ P = param + (size_t)b * N_ * R_;

  __shared__ float As[32][132];
  __shared__ float Bs[32][132];
  float (*Bsp)[132] = (tile == 1) ? Bs : As;  // diag tiles: B == A

  const int t  = threadIdx.x;
  const int tx = t & 15;   // k dir
  const int ty = t >> 4;   // j dir

  float acc[8][8];
#pragma unroll
  for (int i = 0; i < 8; ++i)
#pragma unroll
    for (int j = 0; j < 8; ++j) acc[i][j] = 0.f;

  const int nb = chunk * 512;
  const int ne = nb + 512;
  const int ns = (nb > k0) ? nb : k0;  // rows n < k0 contribute zero (B cols all 0)

  for (int n0 = ns; n0 < ne; n0 += 32) {
#pragma unroll
    for (int m = 0; m < 4; ++m) {
      int idx = t + m * 256;      // 0..1023
      int rr  = idx >> 5;         // 0..31
      int c4  = idx & 31;         // float4 col
      int n   = n0 + rr;
      int gj  = j0 + 4 * c4;
      float4 v = *(const float4*)&P[(size_t)n * R_ + gj];
      float4 o;
      o.x = (n == gj    ) ? 1.f : ((n > gj    ) ? v.x : 0.f);
      o.y = (n == gj + 1) ? 1.f : ((n > gj + 1) ? v.y : 0.f);
      o.z = (n == gj + 2) ? 1.f : ((n > gj + 2) ? v.z : 0.f);
      o.w = (n == gj + 3) ? 1.f : ((n > gj + 3) ? v.w : 0.f);
      *(float4*)&As[rr][4 * c4] = o;
      if (tile == 1) {
        int gk = 128 + 4 * c4;
        float4 u = *(const float4*)&P[(size_t)n * R_ + gk];
        float4 p;
        p.x = (n == gk    ) ? 1.f : ((n > gk    ) ? u.x : 0.f);
        p.y = (n == gk + 1) ? 1.f : ((n > gk + 1) ? u.y : 0.f);
        p.z = (n == gk + 2) ? 1.f : ((n > gk + 2) ? u.z : 0.f);
        p.w = (n == gk + 3) ? 1.f : ((n > gk + 3) ? u.w : 0.f);
        *(float4*)&Bs[rr][4 * c4] = p;
      }
    }
    __syncthreads();
#pragma unroll
    for (int kk = 0; kk < 32; ++kk) {
      float a0[4], a1[4], b0[4], b1[4];
      *(float4*)a0 = *(const float4*)&As[kk][4 * ty];
      *(float4*)a1 = *(const float4*)&As[kk][64 + 4 * ty];
      *(float4*)b0 = *(const float4*)&Bsp[kk][4 * tx];
      *(float4*)b1 = *(const float4*)&Bsp[kk][64 + 4 * tx];
#pragma unroll
      for (int i = 0; i < 4; ++i)
#pragma unroll
        for (int j = 0; j < 4; ++j) {
          acc[i][j]         = fmaf(a0[i], b0[j], acc[i][j]);
          acc[i][j + 4]     = fmaf(a0[i], b1[j], acc[i][j + 4]);
          acc[i + 4][j]     = fmaf(a1[i], b0[j], acc[i + 4][j]);
          acc[i + 4][j + 4] = fmaf(a1[i], b1[j], acc[i + 4][j + 4]);
        }
    }
    __syncthreads();
  }

  float* Sp = SP + (size_t)(chunk * 16 + b) * (R_ * R_);
#pragma unroll
  for (int i = 0; i < 8; ++i) {
    int j = j0 + ((i < 4) ? (4 * ty + i) : (60 + 4 * ty + i));
    *(float4*)&Sp[(size_t)j * R_ + k0 + 4 * tx] =
        make_float4(acc[i][0], acc[i][1], acc[i][2], acc[i][3]);
    *(float4*)&Sp[(size_t)j * R_ + k0 + 64 + 4 * tx] =
        make_float4(acc[i][4], acc[i][5], acc[i][6], acc[i][7]);
  }
}

// ---------------------------------------------------------------------------
// reduce: S = sum over 8 chunks of SP. grid 1024, block 256 (float4 each).
// ---------------------------------------------------------------------------
__global__ __launch_bounds__(256) void reduce_kernel(const float* __restrict__ SP,
                                                     float* __restrict__ S) {
  size_t idx = (size_t)blockIdx.x * 256 + threadIdx.x;  // float4 index
  const float4* sp = (const float4*)SP;
  float4 a = sp[idx];
#pragma unroll
  for (int c = 1; c < 8; ++c) {
    float4 v = sp[idx + (size_t)c * 262144];
    a.x += v.x; a.y += v.y; a.z += v.z; a.w += v.w;
  }
  ((float4*)S)[idx] = a;
}

// ---------------------------------------------------------------------------
// K2: wave-per-column backward substitution.
// wv = blockIdx.x*4 + wave; b = wv>>8; k = wv&255. Lane L owns w[4L..4L+3].
// Per 4-row group: coalesced float4 S-row loads, 4 independent butterfly
// reduces (stale w), then owner-lane correction chain. Writes Wt[b][k][r].
// ---------------------------------------------------------------------------
__global__ __launch_bounds__(256) void solve_kernel(const float* __restrict__ param,
                                                    const float* __restrict__ S,
                                                    float* __restrict__ Wt) {
  const int lane = threadIdx.x & 63;
  const int wv   = blockIdx.x * 4 + (threadIdx.x >> 6);
  const int b    = wv >> 8;
  const int k    = wv & 255;
  const float* __restrict__ Sb = S + (size_t)b * R_ * R_;
  const float* __restrict__ Pb = param + (size_t)b * N_ * R_;

  float4 x = *(const float4*)(Pb + (size_t)k * R_ + 4 * lane);
  {
    int c0 = 4 * lane;
    x.x = (c0     == k) ? 1.f : ((c0     < k) ? x.x : 0.f);
    x.y = (c0 + 1 == k) ? 1.f : ((c0 + 1 < k) ? x.y : 0.f);
    x.z = (c0 + 2 == k) ? 1.f : ((c0 + 2 < k) ? x.z : 0.f);
    x.w = (c0 + 3 == k) ? 1.f : ((c0 + 3 < k) ? x.w : 0.f);
  }
  float4 w = make_float4(0.f, 0.f, 0.f, 0.f);

  const int k4 = k >> 2;
  const float4* Srow = (const float4*)Sb;

  float4 rA0 = Srow[(size_t)(4 * k4 + 0) * 64 + lane];
  float4 rA1 = Srow[(size_t)(4 * k4 + 1) * 64 + lane];
  float4 rA2 = Srow[(size_t)(4 * k4 + 2) * 64 + lane];
  float4 rA3 = Srow[(size_t)(4 * k4 + 3) * 64 + lane];

  for (int r4 = k4;; --r4) {
    const bool more = (r4 > 0);
    float4 rB0, rB1, rB2, rB3;
    if (more) {
      rB0 = Srow[(size_t)(4 * r4 - 4) * 64 + lane];
      rB1 = Srow[(size_t)(4 * r4 - 3) * 64 + lane];
      rB2 = Srow[(size_t)(4 * r4 - 2) * 64 + lane];
      rB3 = Srow[(size_t)(4 * r4 - 1) * 64 + lane];
    }
    float s0 = fmaf(rA0.x, w.x, fmaf(rA0.y, w.y, fmaf(rA0.z, w.z, rA0.w * w.w)));
    float s1 = fmaf(rA1.x, w.x, fmaf(rA1.y, w.y, fmaf(rA1.z, w.z, rA1.w * w.w)));
    float s2 = fmaf(rA2.x, w.x, fmaf(rA2.y, w.y, fmaf(rA2.z, w.z, rA2.w * w.w)));
    float s3 = fmaf(rA3.x, w.x, fmaf(rA3.y, w.y, fmaf(rA3.z, w.z, rA3.w * w.w)));
#pragma unroll
    for (int m = 1; m < 64; m <<= 1) {
      s0 += __shfl_xor(s0, m);
      s1 += __shfl_xor(s1, m);
      s2 += __shfl_xor(s2, m);
      s3 += __shfl_xor(s3, m);
    }
    float w3 = 2.f * __builtin_amdgcn_rcpf(rA3.w) * (x.w - s3);
    float s2c = fmaf(rA2.w, w3, s2);
    float w2 = 2.f * __builtin_amdgcn_rcpf(rA2.z) * (x.z - s2c);
    float s1c = fmaf(rA1.z, w2, fmaf(rA1.w, w3, s1));
    float w1 = 2.f * __builtin_amdgcn_rcpf(rA1.y) * (x.y - s1c);
    float s0c = fmaf(rA0.y, w1, fmaf(rA0.z, w2, fmaf(rA0.w, w3, s0)));
    float w0 = 2.f * __builtin_amdgcn_rcpf(rA0.x) * (x.x - s0c);
    if (lane == r4) { w.w = w3; w.z = w2; w.y = w1; w.x = w0; }

    if (!more) break;
    rA0 = rB0; rA1 = rB1; rA2 = rB2; rA3 = rB3;
  }

  *(float4*)(Wt + ((size_t)b * R_ + k) * R_ + 4 * lane) = w;
}

// ---------------------------------------------------------------------------
// K3: Q = E - V @ W. grid (32, 2, 16), block 256, 128x128 tile, 8x8/thread.
// Reads transposed Wt. j-loop capped at k0+128 (W upper-triangular).
// NO occupancy clamp: 8x8 acc needs ~150 VGPRs (R2's (256,4) forced VGPR=64
// -> acc spilled to scratch -> 890 MB of fake HBM traffic).
// ---------------------------------------------------------------------------
__global__ __launch_bounds__(256) void final_kernel(const float* __restrict__ param,
                                                    const float* __restrict__ Wt,
                                                    float* __restrict__ Q) {
  const int b  = blockIdx.z;
  const int n0 = blockIdx.x * 128;
  const int k0 = blockIdx.y * 128;
  const float* __restrict__ Pb = param + (size_t)b * N_ * R_;
  const float* __restrict__ Wb = Wt + (size_t)b * R_ * R_;  // Wb[k*256+j] = W[j][k]
  float* __restrict__ Qb = Q + (size_t)b * N_ * R_;

  __shared__ float Vs[32][132];  // [j_sub][n_sub]
  __shared__ float Ws[32][132];  // [j_sub][k_sub]

  const int t  = threadIdx.x;
  const int tx = t & 15;   // k dir
  const int ty = t >> 4;   // n dir

  float acc[8][8];
#pragma unroll
  for (int i = 0; i < 8; ++i)
#pragma unroll
    for (int j = 0; j < 8; ++j) acc[i][j] = 0.f;

  const int jend = k0 + 128;
  for (int jb = 0; jb < jend; jb += 32) {
#pragma unroll
    for (int m = 0; m < 16; ++m) {
      int idx = t + m * 256;
      int j = idx & 31;
      int n = idx >> 5;
      int gn = n0 + n, gj = jb + j;
      float pv = Pb[(size_t)gn * R_ + gj];
      Vs[j][n] = (gn == gj) ? 1.f : ((gn > gj) ? pv : 0.f);
    }
#pragma unroll
    for (int m = 0; m < 16; ++m) {
      int idx = t + m * 256;
      int j = idx & 31;
      int kc = idx >> 5;
      Ws[j][kc] = Wb[(size_t)(k0 + kc) * R_ + (jb + j)];
    }
    __syncthreads();
#pragma unroll
    for (int kk = 0; kk < 32; ++kk) {
      float a0[4], a1[4], w0[4], w1[4];
      *(float4*)a0 = *(const float4*)&Vs[kk][4 * ty];
      *(float4*)a1 = *(const float4*)&Vs[kk][64 + 4 * ty];
      *(float4*)w0 = *(const float4*)&Ws[kk][4 * tx];
      *(float4*)w1 = *(const float4*)&Ws[kk][64 + 4 * tx];
#pragma unroll
      for (int i = 0; i < 4; ++i)
#pragma unroll
        for (int j = 0; j < 4; ++j) {
          acc[i][j]         = fmaf(a0[i], w0[j], acc[i][j]);
          acc[i][j + 4]     = fmaf(a0[i], w1[j], acc[i][j + 4]);
          acc[i + 4][j]     = fmaf(a1[i], w0[j], acc[i + 4][j]);
          acc[i + 4][j + 4] = fmaf(a1[i], w1[j], acc[i + 4][j + 4]);
        }
    }
    __syncthreads();
  }

#pragma unroll
  for (int i = 0; i < 8; ++i) {
    int n = n0 + ((i < 4) ? (4 * ty + i) : (60 + 4 * ty + i));
    float o0[4], o1[4];
#pragma unroll
    for (int j = 0; j < 4; ++j) {
      int kc0 = k0 + 4 * tx + j;
      int kc1 = k0 + 64 + 4 * tx + j;
      o0[j] = ((n == kc0) ? 1.f : 0.f) - acc[i][j];
      o1[j] = ((n == kc1) ? 1.f : 0.f) - acc[i][j + 4];
    }
    *(float4*)&Qb[(size_t)n * R_ + k0 + 4 * tx]      = *(float4*)o0;
    *(float4*)&Qb[(size_t)n * R_ + k0 + 64 + 4 * tx] = *(float4*)o1;
  }
}

extern "C" void kernel_launch(void* const* d_in, const int* in_sizes, int n_in,
                              void* d_out, int out_size, void* d_ws, size_t ws_size,
                              hipStream_t stream) {
  const float* param = (const float*)d_in[0];
  float* Q  = (float*)d_out;
  // d_out layout during pipeline (all overwritten by final_kernel):
  //   [0 .. 1M floats)  : S (4 MB)
  //   [8M .. 16M floats): SP partials, 8 chunks x 16 b x 256 x 256 (32 MB)
  float* S  = Q;
  float* SP = Q + (size_t)8 * 1024 * 1024;
  float* Wt = (float*)d_ws;  // 4 MB transposed W

  gram_kernel<<<dim3(3, 8, B_), 256, 0, stream>>>(param, SP);
  reduce_kernel<<<dim3(1024), 256, 0, stream>>>(SP, S);
  solve_kernel<<<dim3(1024), 256, 0, stream>>>(param, S, Wt);
  final_kernel<<<dim3(32, 2, B_), 256, 0, stream>>>(param, Wt, Q);
}

// Round 4
// 295.940 us; speedup vs baseline: 4.2567x; 1.6362x over previous
//
#include <hip/hip_runtime.h>
#include <stdint.h>

#define B_ 16
#define N_ 4096
#define R_ 256

typedef short bf16x8 __attribute__((ext_vector_type(8)));
typedef float f32x4 __attribute__((ext_vector_type(4)));
typedef uint32_t u32;

// V[b,n,i] = (n==i) ? 1 : (n>i ? param[b,n,i] : 0)
// Pipeline: S = V^T V (split-bf16 MFMA, 3 upper 128x128 tiles, split-n partials)
//  -> reduce -> solve (diag(1/tau)+strictU(S)) W = Vtop^T (wave-per-column,
//  writes W packed hi|lo bf16) -> Q = E - V W (split-bf16 MFMA).
//
// Split representation: fp32 x ~= hi + lo (bf16 each, RNE), packed (hi<<16)|lo
// in one u32. x*y ~= xh*yh + xh*yl + xl*yh (3 MFMAs), rel err ~2^-16.

__device__ __forceinline__ u32 rne16(float x) {
  u32 u = __float_as_uint(x);
  return (u + 0x7fffu + ((u >> 16) & 1u)) >> 16;
}
__device__ __forceinline__ u32 pack_split(float x) {
  u32 h = rne16(x);
  float l = x - __uint_as_float(h << 16);
  return (h << 16) | rne16(l);
}

// Build hi/lo bf16x8 fragments from 8 packed words (k-order preserved).
__device__ __forceinline__ void unpack8(const u32* w, bf16x8& hi, bf16x8& lo) {
  union { u32 u[4]; bf16x8 v; } H, L;
#pragma unroll
  for (int i = 0; i < 4; ++i) {
    u32 a = w[2 * i], b = w[2 * i + 1];
    H.u[i] = (a >> 16) | (b & 0xffff0000u);
    L.u[i] = (a & 0xffffu) | (b << 16);
  }
  hi = H.v; lo = L.v;
}

// Read one A/B fragment pair from a swizzled [row][32-word] LDS tile.
// Lane reads words 8q..8q+7 of `row` (chunks 2q,2q+1, XOR-swizzled by row&7).
__device__ __forceinline__ void read_frag(const u32* rowbase, int row, int q2,
                                          bf16x8& hi, bf16x8& lo) {
  u32 w[8];
  const int s = row & 7;
  *(uint4*)&w[0] = *(const uint4*)(rowbase + (((q2    ) ^ s) << 2));
  *(uint4*)&w[4] = *(const uint4*)(rowbase + (((q2 + 1) ^ s) << 2));
  unpack8(w, hi, lo);
}

__device__ __forceinline__ f32x4 mm3(bf16x8 ah, bf16x8 al, bf16x8 bh, bf16x8 bl,
                                     f32x4 c) {
  c = __builtin_amdgcn_mfma_f32_16x16x32_bf16(al, bh, c, 0, 0, 0);
  c = __builtin_amdgcn_mfma_f32_16x16x32_bf16(ah, bl, c, 0, 0, 0);
  c = __builtin_amdgcn_mfma_f32_16x16x32_bf16(ah, bh, c, 0, 0, 0);
  return c;
}

// ---------------------------------------------------------------------------
// K1: partial Gram via MFMA. grid (3 tiles, 8 n-chunks of 512, 16 b), 256 thr.
// tile0=(0,0) tile1=(0,128) tile2=(128,128).
// LDS: VT[col-slot][n-word] packed u32, XOR-swizzled; slots 0..127 = A cols,
// 128..255 = B cols (tile1 only; diag tiles read B from the A slots).
// Writes SP[chunk][b][256][256] fp32 (only the 3 tiles).
// ---------------------------------------------------------------------------
__global__ __launch_bounds__(256) void gram_kernel(const float* __restrict__ param,
                                                   float* __restrict__ SP) {
  const int tile = blockIdx.x, chunk = blockIdx.y, b = blockIdx.z;
  const int j0 = (tile == 2) ? 128 : 0;
  const int k0 = (tile == 0) ? 0 : 128;
  const float* __restrict__ P = param + (size_t)b * N_ * R_;

  __shared__ u32 VT[256][32];

  const int t = threadIdx.x;
  const int lane = t & 63, wv = t >> 6;
  const int wr = wv >> 1, wc = wv & 1;
  const int l15 = lane & 15, q = lane >> 4;
  const int bbase = (tile == 1) ? 128 : 0;

  f32x4 acc[4][4];
#pragma unroll
  for (int i = 0; i < 4; ++i)
#pragma unroll
    for (int j = 0; j < 4; ++j) acc[i][j] = (f32x4){0.f, 0.f, 0.f, 0.f};

  const int nb = chunk * 512;
  const int ns = (nb > k0) ? nb : k0;  // n < k0: B cols all zero -> no contribution
  const int ne = nb + 512;

  for (int n0 = ns; n0 < ne; n0 += 32) {
    // ---- stage: n-fast coalesced loads -> pack -> one b128 per (col, chunk) ----
    if (tile == 1) {
      const int ct = t;          // slot: 0..127 = j-col ct, 128..255 = k-col ct
      const int gc = ct;         // global col (j0=0, k cols are 128..255)
#pragma unroll
      for (int ri = 0; ri < 8; ++ri) {
        u32 qw[4];
#pragma unroll
        for (int s = 0; s < 4; ++s) {
          int n = n0 + 4 * ri + s;
          float p = P[(size_t)n * R_ + gc];
          float v = (n == gc) ? 1.f : ((n > gc) ? p : 0.f);
          qw[s] = pack_split(v);
        }
        *(uint4*)&VT[ct][((ri ^ (ct & 7)) << 2)] = *(uint4*)qw;
      }
    } else {
      const int ct = t & 127;
      const int gc = j0 + ct;
      const int hb = t >> 7;
#pragma unroll
      for (int ri = 0; ri < 4; ++ri) {
        int ch = 2 * ri + hb;
        u32 qw[4];
#pragma unroll
        for (int s = 0; s < 4; ++s) {
          int n = n0 + 4 * ch + s;
          float p = P[(size_t)n * R_ + gc];
          float v = (n == gc) ? 1.f : ((n > gc) ? p : 0.f);
          qw[s] = pack_split(v);
        }
        *(uint4*)&VT[ct][((ch ^ (ct & 7)) << 2)] = *(uint4*)qw;
      }
    }
    __syncthreads();

    // ---- fragments + MFMA ----
    bf16x8 Ah[4], Al[4];
#pragma unroll
    for (int mt = 0; mt < 4; ++mt) {
      int row = 64 * wr + 16 * mt + l15;
      read_frag(&VT[row][0], row, 2 * q, Ah[mt], Al[mt]);
    }
#pragma unroll
    for (int nt = 0; nt < 4; ++nt) {
      int brow = bbase + 64 * wc + 16 * nt + l15;
      bf16x8 bh, bl;
      read_frag(&VT[brow][0], brow, 2 * q, bh, bl);
#pragma unroll
      for (int mt = 0; mt < 4; ++mt)
        acc[mt][nt] = mm3(Ah[mt], Al[mt], bh, bl, acc[mt][nt]);
    }
    __syncthreads();
  }

  // ---- epilogue: C/D layout col=lane&15, row=(lane>>4)*4+reg ----
  float* Sp = SP + (size_t)(chunk * 16 + b) * (R_ * R_);
#pragma unroll
  for (int mt = 0; mt < 4; ++mt)
#pragma unroll
    for (int nt = 0; nt < 4; ++nt) {
      int jj = j0 + 64 * wr + 16 * mt + 4 * q;
      int kk = k0 + 64 * wc + 16 * nt + l15;
#pragma unroll
      for (int r = 0; r < 4; ++r)
        Sp[(size_t)(jj + r) * R_ + kk] = acc[mt][nt][r];
    }
}

// ---------------------------------------------------------------------------
// reduce: S = sum over 8 chunks of SP. grid 1024, block 256 (float4 each).
// ---------------------------------------------------------------------------
__global__ __launch_bounds__(256) void reduce_kernel(const float* __restrict__ SP,
                                                     float* __restrict__ S) {
  size_t idx = (size_t)blockIdx.x * 256 + threadIdx.x;
  const float4* sp = (const float4*)SP;
  float4 a = sp[idx];
#pragma unroll
  for (int c = 1; c < 8; ++c) {
    float4 v = sp[idx + (size_t)c * 262144];
    a.x += v.x; a.y += v.y; a.z += v.z; a.w += v.w;
  }
  ((float4*)S)[idx] = a;
}

// ---------------------------------------------------------------------------
// K2: wave-per-column backward substitution (unchanged math).
// Output: WtP[b][k][j] = packed split-bf16 of W[j][k]  (u32, coalesced x4).
// ---------------------------------------------------------------------------
__global__ __launch_bounds__(256) void solve_kernel(const float* __restrict__ param,
                                                    const float* __restrict__ S,
                                                    u32* __restrict__ WtP) {
  const int lane = threadIdx.x & 63;
  const int wv   = blockIdx.x * 4 + (threadIdx.x >> 6);
  const int b    = wv >> 8;
  const int k    = wv & 255;
  const float* __restrict__ Sb = S + (size_t)b * R_ * R_;
  const float* __restrict__ Pb = param + (size_t)b * N_ * R_;

  float4 x = *(const float4*)(Pb + (size_t)k * R_ + 4 * lane);
  {
    int c0 = 4 * lane;
    x.x = (c0     == k) ? 1.f : ((c0     < k) ? x.x : 0.f);
    x.y = (c0 + 1 == k) ? 1.f : ((c0 + 1 < k) ? x.y : 0.f);
    x.z = (c0 + 2 == k) ? 1.f : ((c0 + 2 < k) ? x.z : 0.f);
    x.w = (c0 + 3 == k) ? 1.f : ((c0 + 3 < k) ? x.w : 0.f);
  }
  float4 w = make_float4(0.f, 0.f, 0.f, 0.f);

  const int k4 = k >> 2;
  const float4* Srow = (const float4*)Sb;

  float4 rA0 = Srow[(size_t)(4 * k4 + 0) * 64 + lane];
  float4 rA1 = Srow[(size_t)(4 * k4 + 1) * 64 + lane];
  float4 rA2 = Srow[(size_t)(4 * k4 + 2) * 64 + lane];
  float4 rA3 = Srow[(size_t)(4 * k4 + 3) * 64 + lane];

  for (int r4 = k4;; --r4) {
    const bool more = (r4 > 0);
    float4 rB0, rB1, rB2, rB3;
    if (more) {
      rB0 = Srow[(size_t)(4 * r4 - 4) * 64 + lane];
      rB1 = Srow[(size_t)(4 * r4 - 3) * 64 + lane];
      rB2 = Srow[(size_t)(4 * r4 - 2) * 64 + lane];
      rB3 = Srow[(size_t)(4 * r4 - 1) * 64 + lane];
    }
    float s0 = fmaf(rA0.x, w.x, fmaf(rA0.y, w.y, fmaf(rA0.z, w.z, rA0.w * w.w)));
    float s1 = fmaf(rA1.x, w.x, fmaf(rA1.y, w.y, fmaf(rA1.z, w.z, rA1.w * w.w)));
    float s2 = fmaf(rA2.x, w.x, fmaf(rA2.y, w.y, fmaf(rA2.z, w.z, rA2.w * w.w)));
    float s3 = fmaf(rA3.x, w.x, fmaf(rA3.y, w.y, fmaf(rA3.z, w.z, rA3.w * w.w)));
#pragma unroll
    for (int m = 1; m < 64; m <<= 1) {
      s0 += __shfl_xor(s0, m);
      s1 += __shfl_xor(s1, m);
      s2 += __shfl_xor(s2, m);
      s3 += __shfl_xor(s3, m);
    }
    float w3 = 2.f * __builtin_amdgcn_rcpf(rA3.w) * (x.w - s3);
    float s2c = fmaf(rA2.w, w3, s2);
    float w2 = 2.f * __builtin_amdgcn_rcpf(rA2.z) * (x.z - s2c);
    float s1c = fmaf(rA1.z, w2, fmaf(rA1.w, w3, s1));
    float w1 = 2.f * __builtin_amdgcn_rcpf(rA1.y) * (x.y - s1c);
    float s0c = fmaf(rA0.y, w1, fmaf(rA0.z, w2, fmaf(rA0.w, w3, s0)));
    float w0 = 2.f * __builtin_amdgcn_rcpf(rA0.x) * (x.x - s0c);
    if (lane == r4) { w.w = w3; w.z = w2; w.y = w1; w.x = w0; }

    if (!more) break;
    rA0 = rB0; rA1 = rB1; rA2 = rB2; rA3 = rB3;
  }

  u32 pw[4] = { pack_split(w.x), pack_split(w.y), pack_split(w.z), pack_split(w.w) };
  *(uint4*)(WtP + ((size_t)b * R_ + k) * R_ + 4 * lane) = *(uint4*)pw;
}

// ---------------------------------------------------------------------------
// K3: Q = E - V @ W via MFMA. grid (32, 2, 16), block 256 (4 waves 2x2).
// 128x128 output tile, BK=32. LDS: VA[row][32] (V packed), WB[krow][32]
// (W packed, from WtP), both XOR-swizzled. j-loop capped at k0+128.
// ---------------------------------------------------------------------------
__global__ __launch_bounds__(256) void final_kernel(const float* __restrict__ param,
                                                    const u32* __restrict__ WtP,
                                                    float* __restrict__ Q) {
  const int b  = blockIdx.z;
  const int n0 = blockIdx.x * 128;
  const int k0 = blockIdx.y * 128;
  const float* __restrict__ Pb = param + (size_t)b * N_ * R_;
  const u32* __restrict__ Wb = WtP + (size_t)b * R_ * R_;
  float* __restrict__ Qb = Q + (size_t)b * N_ * R_;

  __shared__ u32 VA[128][32];
  __shared__ u32 WB[128][32];

  const int t = threadIdx.x;
  const int lane = t & 63, wv = t >> 6;
  const int wr = wv >> 1, wc = wv & 1;
  const int l15 = lane & 15, q = lane >> 4;
  const int row8 = t >> 3;   // 0..31
  const int c4 = t & 7;

  f32x4 acc[4][4];
#pragma unroll
  for (int i = 0; i < 4; ++i)
#pragma unroll
    for (int j = 0; j < 4; ++j) acc[i][j] = (f32x4){0.f, 0.f, 0.f, 0.f};

  const int jend = k0 + 128;
  for (int jb = 0; jb < jend; jb += 32) {
#pragma unroll
    for (int pi = 0; pi < 4; ++pi) {
      int row = row8 + 32 * pi;
      int n = n0 + row;
      int gj = jb + 4 * c4;
      float4 v = *(const float4*)&Pb[(size_t)n * R_ + gj];
      u32 qw[4];
      qw[0] = pack_split((n == gj    ) ? 1.f : ((n > gj    ) ? v.x : 0.f));
      qw[1] = pack_split((n == gj + 1) ? 1.f : ((n > gj + 1) ? v.y : 0.f));
      qw[2] = pack_split((n == gj + 2) ? 1.f : ((n > gj + 2) ? v.z : 0.f));
      qw[3] = pack_split((n == gj + 3) ? 1.f : ((n > gj + 3) ? v.w : 0.f));
      *(uint4*)&VA[row][((c4 ^ (row & 7)) << 2)] = *(uint4*)qw;
      // W tile: already packed in global
      uint4 wq = *(const uint4*)&Wb[(size_t)(k0 + row) * R_ + gj];
      *(uint4*)&WB[row][((c4 ^ (row & 7)) << 2)] = wq;
    }
    __syncthreads();

    bf16x8 Ah[4], Al[4];
#pragma unroll
    for (int mt = 0; mt < 4; ++mt) {
      int row = 64 * wr + 16 * mt + l15;
      read_frag(&VA[row][0], row, 2 * q, Ah[mt], Al[mt]);
    }
#pragma unroll
    for (int nt = 0; nt < 4; ++nt) {
      int krow = 64 * wc + 16 * nt + l15;
      bf16x8 bh, bl;
      read_frag(&WB[krow][0], krow, 2 * q, bh, bl);
#pragma unroll
      for (int mt = 0; mt < 4; ++mt)
        acc[mt][nt] = mm3(Ah[mt], Al[mt], bh, bl, acc[mt][nt]);
    }
    __syncthreads();
  }

#pragma unroll
  for (int mt = 0; mt < 4; ++mt)
#pragma unroll
    for (int nt = 0; nt < 4; ++nt) {
      int nrow = n0 + 64 * wr + 16 * mt + 4 * q;
      int kcol = k0 + 64 * wc + 16 * nt + l15;
#pragma unroll
      for (int r = 0; r < 4; ++r) {
        float val = ((nrow + r == kcol) ? 1.f : 0.f) - acc[mt][nt][r];
        Qb[(size_t)(nrow + r) * R_ + kcol] = val;
      }
    }
}

extern "C" void kernel_launch(void* const* d_in, const int* in_sizes, int n_in,
                              void* d_out, int out_size, void* d_ws, size_t ws_size,
                              hipStream_t stream) {
  const float* param = (const float*)d_in[0];
  float* Q  = (float*)d_out;
  // d_out layout during pipeline (all overwritten by final_kernel):
  //   [0 .. 1M floats)  : S (4 MB)
  //   [8M .. 16M floats): SP partials, 8 chunks x 16 b x 256 x 256 (32 MB)
  float* S  = Q;
  float* SP = Q + (size_t)8 * 1024 * 1024;
  u32*   WtP = (u32*)d_ws;  // 4 MB packed split-bf16 W^T

  gram_kernel<<<dim3(3, 8, B_), 256, 0, stream>>>(param, SP);
  reduce_kernel<<<dim3(1024), 256, 0, stream>>>(SP, S);
  solve_kernel<<<dim3(1024), 256, 0, stream>>>(param, S, WtP);
  final_kernel<<<dim3(32, 2, B_), 256, 0, stream>>>(param, WtP, Q);
}

// Round 5
// 184.813 us; speedup vs baseline: 6.8162x; 1.6013x over previous
//
#include <hip/hip_runtime.h>
#include <stdint.h>

#define B_ 16
#define N_ 4096
#define R_ 256

typedef short bf16x8 __attribute__((ext_vector_type(8)));
typedef float f32x4 __attribute__((ext_vector_type(4)));
typedef uint32_t u32;

// V[b,n,i] = (n==i) ? 1 : (n>i ? param[b,n,i] : 0)
// Pipeline: S = V^T V (split-bf16 MFMA, 3 upper 128x128 tiles, 16 n-chunk
// partials filling d_out) -> reduce (in-place into chunk 0 => S = d_out base)
// -> solve (diag(1/tau)+strictU(S)) W = Vtop^T (wave-per-column, W packed
// hi|lo bf16 into d_ws) -> Q = E - V W (split-bf16 MFMA, overwrites d_out).
//
// Split: fp32 x ~= hi + lo, both TRUNCATED bf16 (5 VALU ops; lo = x - hi is
// exact, trunc err ~2^-16|x|). x*y ~= xh*yh + xh*yl + xl*yh (3 MFMAs).

__device__ __forceinline__ u32 pack_split(float x) {
  u32 u = __float_as_uint(x);
  u32 h = u & 0xffff0000u;           // hi = trunc bf16
  float l = x - __uint_as_float(h);  // exact remainder
  return h | (__float_as_uint(l) >> 16);
}

// Build hi/lo bf16x8 fragments from 8 packed words (k-order preserved).
__device__ __forceinline__ void unpack8(const u32* w, bf16x8& hi, bf16x8& lo) {
  union { u32 u[4]; bf16x8 v; } H, L;
#pragma unroll
  for (int i = 0; i < 4; ++i) {
    u32 a = w[2 * i], b = w[2 * i + 1];
    H.u[i] = (a >> 16) | (b & 0xffff0000u);
    L.u[i] = (a & 0xffffu) | (b << 16);
  }
  hi = H.v; lo = L.v;
}

// Read one A/B fragment pair from a swizzled [row][32-word] LDS tile.
__device__ __forceinline__ void read_frag(const u32* rowbase, int row, int q2,
                                          bf16x8& hi, bf16x8& lo) {
  u32 w[8];
  const int s = row & 7;
  *(uint4*)&w[0] = *(const uint4*)(rowbase + (((q2    ) ^ s) << 2));
  *(uint4*)&w[4] = *(const uint4*)(rowbase + (((q2 + 1) ^ s) << 2));
  unpack8(w, hi, lo);
}

__device__ __forceinline__ f32x4 mm3(bf16x8 ah, bf16x8 al, bf16x8 bh, bf16x8 bl,
                                     f32x4 c) {
  c = __builtin_amdgcn_mfma_f32_16x16x32_bf16(al, bh, c, 0, 0, 0);
  c = __builtin_amdgcn_mfma_f32_16x16x32_bf16(ah, bl, c, 0, 0, 0);
  c = __builtin_amdgcn_mfma_f32_16x16x32_bf16(ah, bh, c, 0, 0, 0);
  return c;
}

// ---------------------------------------------------------------------------
// K1: partial Gram via MFMA. grid (3 tiles, 16 n-chunks of 256, 16 b), 256 thr.
// tile0=(0,0) tile1=(0,128) tile2=(128,128).
// T14 prefetch: next iter's global loads issued before the MFMA phase so HBM
// latency hides under compute. Writes SP[chunk][b][256][256] (3 tiles only).
// ---------------------------------------------------------------------------
__global__ __launch_bounds__(256) void gram_kernel(const float* __restrict__ param,
                                                   float* __restrict__ SP) {
  const int tile = blockIdx.x, chunk = blockIdx.y, b = blockIdx.z;
  const int j0 = (tile == 2) ? 128 : 0;
  const int k0 = (tile == 0) ? 0 : 128;
  const float* __restrict__ P = param + (size_t)b * N_ * R_;

  __shared__ u32 VT[256][32];

  const int t = threadIdx.x;
  const int lane = t & 63, wv = t >> 6;
  const int wr = wv >> 1, wc = wv & 1;
  const int l15 = lane & 15, q = lane >> 4;
  const int bbase = (tile == 1) ? 128 : 0;

  f32x4 acc[4][4];
#pragma unroll
  for (int i = 0; i < 4; ++i)
#pragma unroll
    for (int j = 0; j < 4; ++j) acc[i][j] = (f32x4){0.f, 0.f, 0.f, 0.f};

  const int nb = chunk * 256;
  const int ns = (nb > k0) ? nb : k0;  // n < k0: B cols all zero
  const int ne = nb + 256;

  // staging register file (tile1 uses 32, others 16)
  float ld[32];

  const int ct1 = t;                    // tile1 slot/col
  const int ct0 = t & 127;              // tile0/2 slot
  const int gc0 = j0 + ct0;
  const int hb  = t >> 7;

  auto do_load = [&](int n0) {
    if (tile == 1) {
#pragma unroll
      for (int ri = 0; ri < 8; ++ri)
#pragma unroll
        for (int s = 0; s < 4; ++s)
          ld[4 * ri + s] = P[(size_t)(n0 + 4 * ri + s) * R_ + ct1];
    } else {
#pragma unroll
      for (int ri = 0; ri < 4; ++ri)
#pragma unroll
        for (int s = 0; s < 4; ++s)
          ld[4 * ri + s] = P[(size_t)(n0 + 4 * (2 * ri + hb) + s) * R_ + gc0];
    }
  };

  auto do_write = [&](int n0) {
    if (tile == 1) {
#pragma unroll
      for (int ri = 0; ri < 8; ++ri) {
        u32 qw[4];
#pragma unroll
        for (int s = 0; s < 4; ++s) {
          int n = n0 + 4 * ri + s;
          float v = (n == ct1) ? 1.f : ((n > ct1) ? ld[4 * ri + s] : 0.f);
          qw[s] = pack_split(v);
        }
        *(uint4*)&VT[ct1][((ri ^ (ct1 & 7)) << 2)] = *(uint4*)qw;
      }
    } else {
#pragma unroll
      for (int ri = 0; ri < 4; ++ri) {
        int ch = 2 * ri + hb;
        u32 qw[4];
#pragma unroll
        for (int s = 0; s < 4; ++s) {
          int n = n0 + 4 * ch + s;
          float v = (n == gc0) ? 1.f : ((n > gc0) ? ld[4 * ri + s] : 0.f);
          qw[s] = pack_split(v);
        }
        *(uint4*)&VT[ct0][((ch ^ (ct0 & 7)) << 2)] = *(uint4*)qw;
      }
    }
  };

  do_load(ns);
  for (int n0 = ns; n0 < ne; n0 += 32) {
    do_write(n0);
    __syncthreads();
    if (n0 + 32 < ne) do_load(n0 + 32);  // prefetch: overlaps MFMA below

    bf16x8 Ah[4], Al[4];
#pragma unroll
    for (int mt = 0; mt < 4; ++mt) {
      int row = 64 * wr + 16 * mt + l15;
      read_frag(&VT[row][0], row, 2 * q, Ah[mt], Al[mt]);
    }
#pragma unroll
    for (int nt = 0; nt < 4; ++nt) {
      int brow = bbase + 64 * wc + 16 * nt + l15;
      bf16x8 bh, bl;
      read_frag(&VT[brow][0], brow, 2 * q, bh, bl);
#pragma unroll
      for (int mt = 0; mt < 4; ++mt)
        acc[mt][nt] = mm3(Ah[mt], Al[mt], bh, bl, acc[mt][nt]);
    }
    __syncthreads();
  }

  // C/D layout: col=lane&15, row=(lane>>4)*4+reg
  float* Sp = SP + (size_t)(chunk * 16 + b) * (R_ * R_);
#pragma unroll
  for (int mt = 0; mt < 4; ++mt)
#pragma unroll
    for (int nt = 0; nt < 4; ++nt) {
      int jj = j0 + 64 * wr + 16 * mt + 4 * q;
      int kk = k0 + 64 * wc + 16 * nt + l15;
#pragma unroll
      for (int r = 0; r < 4; ++r)
        Sp[(size_t)(jj + r) * R_ + kk] = acc[mt][nt][r];
    }
}

// ---------------------------------------------------------------------------
// reduce: S = sum over 16 chunks of SP, IN PLACE into chunk-0 slot.
// grid 1024, block 256 (one float4 each).
// ---------------------------------------------------------------------------
__global__ __launch_bounds__(256) void reduce_kernel(float* __restrict__ SP) {
  size_t idx = (size_t)blockIdx.x * 256 + threadIdx.x;  // float4 index
  float4* sp = (float4*)SP;
  float4 a = sp[idx];
#pragma unroll
  for (int c = 1; c < 16; ++c) {
    float4 v = sp[idx + (size_t)c * 262144];
    a.x += v.x; a.y += v.y; a.z += v.z; a.w += v.w;
  }
  sp[idx] = a;
}

// ---------------------------------------------------------------------------
// K2: wave-per-column backward substitution (unchanged math).
// Output: WtP[b][k][j] = packed split-bf16 of W[j][k].
// ---------------------------------------------------------------------------
__global__ __launch_bounds__(256) void solve_kernel(const float* __restrict__ param,
                                                    const float* __restrict__ S,
                                                    u32* __restrict__ WtP) {
  const int lane = threadIdx.x & 63;
  const int wv   = blockIdx.x * 4 + (threadIdx.x >> 6);
  const int b    = wv >> 8;
  const int k    = wv & 255;
  const float* __restrict__ Sb = S + (size_t)b * R_ * R_;
  const float* __restrict__ Pb = param + (size_t)b * N_ * R_;

  float4 x = *(const float4*)(Pb + (size_t)k * R_ + 4 * lane);
  {
    int c0 = 4 * lane;
    x.x = (c0     == k) ? 1.f : ((c0     < k) ? x.x : 0.f);
    x.y = (c0 + 1 == k) ? 1.f : ((c0 + 1 < k) ? x.y : 0.f);
    x.z = (c0 + 2 == k) ? 1.f : ((c0 + 2 < k) ? x.z : 0.f);
    x.w = (c0 + 3 == k) ? 1.f : ((c0 + 3 < k) ? x.w : 0.f);
  }
  float4 w = make_float4(0.f, 0.f, 0.f, 0.f);

  const int k4 = k >> 2;
  const float4* Srow = (const float4*)Sb;

  float4 rA0 = Srow[(size_t)(4 * k4 + 0) * 64 + lane];
  float4 rA1 = Srow[(size_t)(4 * k4 + 1) * 64 + lane];
  float4 rA2 = Srow[(size_t)(4 * k4 + 2) * 64 + lane];
  float4 rA3 = Srow[(size_t)(4 * k4 + 3) * 64 + lane];

  for (int r4 = k4;; --r4) {
    const bool more = (r4 > 0);
    float4 rB0, rB1, rB2, rB3;
    if (more) {
      rB0 = Srow[(size_t)(4 * r4 - 4) * 64 + lane];
      rB1 = Srow[(size_t)(4 * r4 - 3) * 64 + lane];
      rB2 = Srow[(size_t)(4 * r4 - 2) * 64 + lane];
      rB3 = Srow[(size_t)(4 * r4 - 1) * 64 + lane];
    }
    float s0 = fmaf(rA0.x, w.x, fmaf(rA0.y, w.y, fmaf(rA0.z, w.z, rA0.w * w.w)));
    float s1 = fmaf(rA1.x, w.x, fmaf(rA1.y, w.y, fmaf(rA1.z, w.z, rA1.w * w.w)));
    float s2 = fmaf(rA2.x, w.x, fmaf(rA2.y, w.y, fmaf(rA2.z, w.z, rA2.w * w.w)));
    float s3 = fmaf(rA3.x, w.x, fmaf(rA3.y, w.y, fmaf(rA3.z, w.z, rA3.w * w.w)));
#pragma unroll
    for (int m = 1; m < 64; m <<= 1) {
      s0 += __shfl_xor(s0, m);
      s1 += __shfl_xor(s1, m);
      s2 += __shfl_xor(s2, m);
      s3 += __shfl_xor(s3, m);
    }
    float w3 = 2.f * __builtin_amdgcn_rcpf(rA3.w) * (x.w - s3);
    float s2c = fmaf(rA2.w, w3, s2);
    float w2 = 2.f * __builtin_amdgcn_rcpf(rA2.z) * (x.z - s2c);
    float s1c = fmaf(rA1.z, w2, fmaf(rA1.w, w3, s1));
    float w1 = 2.f * __builtin_amdgcn_rcpf(rA1.y) * (x.y - s1c);
    float s0c = fmaf(rA0.y, w1, fmaf(rA0.z, w2, fmaf(rA0.w, w3, s0)));
    float w0 = 2.f * __builtin_amdgcn_rcpf(rA0.x) * (x.x - s0c);
    if (lane == r4) { w.w = w3; w.z = w2; w.y = w1; w.x = w0; }

    if (!more) break;
    rA0 = rB0; rA1 = rB1; rA2 = rB2; rA3 = rB3;
  }

  u32 pw[4] = { pack_split(w.x), pack_split(w.y), pack_split(w.z), pack_split(w.w) };
  *(uint4*)(WtP + ((size_t)b * R_ + k) * R_ + 4 * lane) = *(uint4*)pw;
}

// ---------------------------------------------------------------------------
// K3: Q = E - V @ W via MFMA. grid (32, 2, 16), block 256 (4 waves 2x2).
// 128x128 output tile, BK=32. LDS VA/WB XOR-swizzled packed u32.
// ---------------------------------------------------------------------------
__global__ __launch_bounds__(256) void final_kernel(const float* __restrict__ param,
                                                    const u32* __restrict__ WtP,
                                                    float* __restrict__ Q) {
  const int b  = blockIdx.z;
  const int n0 = blockIdx.x * 128;
  const int k0 = blockIdx.y * 128;
  const float* __restrict__ Pb = param + (size_t)b * N_ * R_;
  const u32* __restrict__ Wb = WtP + (size_t)b * R_ * R_;
  float* __restrict__ Qb = Q + (size_t)b * N_ * R_;

  __shared__ u32 VA[128][32];
  __shared__ u32 WB[128][32];

  const int t = threadIdx.x;
  const int lane = t & 63, wv = t >> 6;
  const int wr = wv >> 1, wc = wv & 1;
  const int l15 = lane & 15, q = lane >> 4;
  const int row8 = t >> 3;   // 0..31
  const int c4 = t & 7;

  f32x4 acc[4][4];
#pragma unroll
  for (int i = 0; i < 4; ++i)
#pragma unroll
    for (int j = 0; j < 4; ++j) acc[i][j] = (f32x4){0.f, 0.f, 0.f, 0.f};

  const int jend = k0 + 128;
  for (int jb = 0; jb < jend; jb += 32) {
#pragma unroll
    for (int pi = 0; pi < 4; ++pi) {
      int row = row8 + 32 * pi;
      int n = n0 + row;
      int gj = jb + 4 * c4;
      float4 v = *(const float4*)&Pb[(size_t)n * R_ + gj];
      u32 qw[4];
      qw[0] = pack_split((n == gj    ) ? 1.f : ((n > gj    ) ? v.x : 0.f));
      qw[1] = pack_split((n == gj + 1) ? 1.f : ((n > gj + 1) ? v.y : 0.f));
      qw[2] = pack_split((n == gj + 2) ? 1.f : ((n > gj + 2) ? v.z : 0.f));
      qw[3] = pack_split((n == gj + 3) ? 1.f : ((n > gj + 3) ? v.w : 0.f));
      *(uint4*)&VA[row][((c4 ^ (row & 7)) << 2)] = *(uint4*)qw;
      uint4 wq = *(const uint4*)&Wb[(size_t)(k0 + row) * R_ + gj];
      *(uint4*)&WB[row][((c4 ^ (row & 7)) << 2)] = wq;
    }
    __syncthreads();

    bf16x8 Ah[4], Al[4];
#pragma unroll
    for (int mt = 0; mt < 4; ++mt) {
      int row = 64 * wr + 16 * mt + l15;
      read_frag(&VA[row][0], row, 2 * q, Ah[mt], Al[mt]);
    }
#pragma unroll
    for (int nt = 0; nt < 4; ++nt) {
      int krow = 64 * wc + 16 * nt + l15;
      bf16x8 bh, bl;
      read_frag(&WB[krow][0], krow, 2 * q, bh, bl);
#pragma unroll
      for (int mt = 0; mt < 4; ++mt)
        acc[mt][nt] = mm3(Ah[mt], Al[mt], bh, bl, acc[mt][nt]);
    }
    __syncthreads();
  }

#pragma unroll
  for (int mt = 0; mt < 4; ++mt)
#pragma unroll
    for (int nt = 0; nt < 4; ++nt) {
      int nrow = n0 + 64 * wr + 16 * mt + 4 * q;
      int kcol = k0 + 64 * wc + 16 * nt + l15;
#pragma unroll
      for (int r = 0; r < 4; ++r) {
        float val = ((nrow + r == kcol) ? 1.f : 0.f) - acc[mt][nt][r];
        Qb[(size_t)(nrow + r) * R_ + kcol] = val;
      }
    }
}

extern "C" void kernel_launch(void* const* d_in, const int* in_sizes, int n_in,
                              void* d_out, int out_size, void* d_ws, size_t ws_size,
                              hipStream_t stream) {
  const float* param = (const float*)d_in[0];
  float* Q  = (float*)d_out;
  // d_out during pipeline: SP = 16 chunks x 16 b x 256x256 fp32 = the WHOLE
  // 64 MB of d_out. reduce sums chunks 1..15 into chunk 0 in place, so
  // S = d_out base. final_kernel then overwrites all of d_out with Q.
  float* SP = Q;
  float* S  = Q;
  u32*   WtP = (u32*)d_ws;  // 4 MB packed split-bf16 W^T

  gram_kernel<<<dim3(3, 16, B_), 256, 0, stream>>>(param, SP);
  reduce_kernel<<<dim3(1024), 256, 0, stream>>>(SP);
  solve_kernel<<<dim3(1024), 256, 0, stream>>>(param, S, WtP);
  final_kernel<<<dim3(32, 2, B_), 256, 0, stream>>>(param, WtP, Q);
}